// Round 7
// baseline (46.215 us; speedup 1.0000x reference)
//
#include <hip/hip_runtime.h>
#include <hip/hip_fp16.h>

typedef _Float16 h2 __attribute__((ext_vector_type(2)));
typedef float f2 __attribute__((ext_vector_type(2)));

#define NCH   2048                 // chunks (one single-wave workgroup each)
#define CL    128                  // outputs per chunk
#define HALO  32                   // warm-up steps
#define SPB   8                    // steps per block
#define NB    20                   // (HALO+CL)/SPB
#define BH    4                    // halo blocks
#define TROW  141                  // traj row stride in dwords (odd -> conflict-free)

#if __has_builtin(__builtin_amdgcn_exp2f)
#define EXP2F __builtin_amdgcn_exp2f
#else
#define EXP2F exp2f
#endif
#if __has_builtin(__builtin_amdgcn_rcpf)
#define RCPF __builtin_amdgcn_rcpf
#else
#define RCPF(x) (1.0f / (x))
#endif

#define A_K   (-14.4269504088896341f)   /* -10*log2(e) */
#define UPC_K (7.21347520444481704f)    /* -A_K*0.5    */
#define K2_K  (2.8853900817779268f)     /* 2*log2(e)   */

__device__ __forceinline__ h2 pkrtz(float a, float b) {
    return __builtin_bit_cast(h2, __builtin_amdgcn_cvt_pkrtz(a, b));
}
__device__ __forceinline__ float sigstep(float w, float up) {
    return RCPF(1.0f + EXP2F(__builtin_fmaf(A_K, w, up)));
}
__device__ __forceinline__ float fold(float u) {
    return __builtin_fmaf(A_K, u, UPC_K);
}
__device__ __forceinline__ uint32_t pk16(float a, float b) {
    return __builtin_bit_cast(uint32_t, pkrtz(a, b));
}
__device__ __forceinline__ h2 ldw(uint32_t v) {
    return __builtin_bit_cast(h2, v);
}
__device__ __forceinline__ h2 tanh2(h2 a) {
    float z0 = (float)a[0], z1 = (float)a[1];
    float t0 = 1.0f - 2.0f * RCPF(1.0f + EXP2F(K2_K * z0));
    float t1 = 1.0f - 2.0f * RCPF(1.0f + EXP2F(K2_K * z1));
    return pkrtz(t0, t1);
}

#define STR2(x) #x
#define WAITVMn(N) asm volatile("s_waitcnt vmcnt(" STR2(N) ")" ::: "memory")

__global__ void __launch_bounds__(64)
fastnet_kernel(const float* __restrict__ x, const float* __restrict__ u,
               const float* __restrict__ W1, const float* __restrict__ W2,
               const float* __restrict__ W3, float* __restrict__ out) {
    __shared__ uint32_t traj[8 * TROW];   // 4.5 KB: ONLY LDS in the kernel

    const int  lane  = threadIdx.x;
    const int  ch    = blockIdx.x;
    const long cbase = (long)ch * CL;
    const float* su  = u + (cbase - (long)HALO) * 140;
    const int  cl    = (lane < 12) ? lane : 11;   // clamp for the 12-wide tail

    // ---- initial weights: chunk 0 exact, others converge through the halo ----
    float wa, wb, wc;
    if (ch == 0) {
        wa = (lane < 30) ? W1[lane] : (lane < 130 ? W2[lane - 30] : W3[lane - 130]);
        wb = W2[lane + 34];
        int kc = lane + 128;
        wc = (lane < 12) ? ((kc < 130) ? W2[kc - 30] : W3[kc - 130]) : 0.5f;
    } else {
        wa = wb = wc = 0.5f;
    }

    // triple-buffered u register sets (block b -> set b%3): 72 VGPR
    float aU0[SPB], aU1[SPB], aU2[SPB];
    float bU0[SPB], bU1[SPB], bU2[SPB];
    float cU0[SPB], cU1[SPB], cU2[SPB];
    f2 xE[3], xO[3];                      // x ping-pong (round r -> r&1)

    // 24 coalesced dword loads: row reads ARE the right lane distribution
#define ISSUE_L(B_, U0, U1, U2) do {                                            \
        const float* p_ = su + (long)(B_) * (SPB * 140);                        \
        _Pragma("unroll")                                                       \
        for (int t = 0; t < SPB; t++) {                                         \
            U0[t] = p_[t * 140 + lane];                                         \
            U1[t] = p_[t * 140 + 64 + lane];                                    \
            U2[t] = p_[t * 140 + 128 + cl];                                     \
        }                                                                       \
    } while (0)

    // x for PB round R_ (lanes 0..7, 2 outputs each): 3 vm events
#define ISSUE_X(R_, XS_) do {                                                   \
        if (lane < 8) {                                                         \
            const float* xp_ = x + (cbase + (long)(R_) * 16 + 2 * lane) * 3;    \
            XS_[0] = *(const f2*)(xp_);                                         \
            XS_[1] = *(const f2*)(xp_ + 2);                                     \
            XS_[2] = *(const f2*)(xp_ + 4);                                     \
        }                                                                       \
    } while (0)

    // one 8-step block: [x issue][u issue b+2][counted wait][recurrence][PB]
#define BLK(B_, N_, UC0, UC1, UC2, UL0, UL1, UL2, XR_, XSI_, PBR_, XSC_, TRAJ_) do { \
        if ((XR_) >= 0) ISSUE_X(XR_, XSI_);                                     \
        if ((B_) + 2 < NB) ISSUE_L((B_) + 2, UL0, UL1, UL2);                    \
        WAITVMn(N_);                                                            \
        _Pragma("unroll")                                                       \
        for (int t = 0; t < SPB; t += 2) {                                      \
            wa = sigstep(wa, fold(UC0[t]));                                     \
            wb = sigstep(wb, fold(UC1[t]));                                     \
            wc = sigstep(wc, fold(UC2[t]));                                     \
            float wa0 = wa, wb0 = wb, wc0 = wc;                                 \
            wa = sigstep(wa, fold(UC0[t + 1]));                                 \
            wb = sigstep(wb, fold(UC1[t + 1]));                                 \
            wc = sigstep(wc, fold(UC2[t + 1]));                                 \
            if (TRAJ_) {                                                        \
                uint32_t* tw = &traj[((((B_) - BH) & 1) * 4 + (t >> 1)) * TROW + lane]; \
                tw[0]  = pk16(wa0, wa);                                         \
                tw[64] = pk16(wb0, wb);                                         \
                if (lane < 12) tw[128] = pk16(wc0, wc);                         \
            }                                                                   \
        }                                                                       \
        if ((PBR_) >= 0 && lane < 8) {                                          \
            h2 xq0 = pkrtz(XSC_[0][0], XSC_[1][1]);                             \
            h2 xq1 = pkrtz(XSC_[0][1], XSC_[2][0]);                             \
            h2 xq2 = pkrtz(XSC_[1][0], XSC_[2][1]);                             \
            const uint32_t* tr_ = &traj[lane * TROW];                           \
            h2 h1[10];                                                          \
            _Pragma("unroll")                                                   \
            for (int cc = 0; cc < 10; cc++) {                                   \
                h2 acc = ldw(tr_[cc]) * xq0;                                    \
                acc += ldw(tr_[10 + cc]) * xq1;                                 \
                acc += ldw(tr_[20 + cc]) * xq2;                                 \
                h1[cc] = tanh2(acc);                                            \
            }                                                                   \
            h2 hh[10];                                                          \
            _Pragma("unroll")                                                   \
            for (int cc = 0; cc < 10; cc++) {                                   \
                h2 acc = h1[0] * ldw(tr_[30 + cc]);                             \
                _Pragma("unroll")                                               \
                for (int r2 = 1; r2 < 10; r2++)                                 \
                    acc += h1[r2] * ldw(tr_[30 + r2 * 10 + cc]);                \
                hh[cc] = tanh2(acc);                                            \
            }                                                                   \
            h2 ya = hh[0] * ldw(tr_[130]);                                      \
            _Pragma("unroll")                                                   \
            for (int r2 = 1; r2 < 10; r2++) ya += hh[r2] * ldw(tr_[130 + r2]);  \
            long g0_ = cbase + (long)(PBR_) * 16 + 2 * lane;                    \
            f2 o_; o_[0] = (float)ya[0]; o_[1] = (float)ya[1];                  \
            *reinterpret_cast<f2*>(out + g0_) = o_;                             \
        }                                                                       \
    } while (0)

    // ---- prologue: 2 blocks of u in flight (x5 issued FIRST for ch0 ledger) ----
    if (ch != 0) {
        ISSUE_L(0, aU0, aU1, aU2);
        ISSUE_L(1, bU0, bU1, bU2);
    } else {
        ISSUE_X(0, xE);
        ISSUE_L(4, bU0, bU1, bU2);
        ISSUE_L(5, cU0, cU1, cU2);
    }

    // ---- halo blocks (ch != 0 only) ----
    if (ch != 0) {
        BLK(0, 48, aU0,aU1,aU2, cU0,cU1,cU2, -1, xE, -1, xE, 0);
        BLK(1, 48, bU0,bU1,bU2, aU0,aU1,aU2, -1, xE, -1, xE, 0);
        BLK(2, 48, cU0,cU1,cU2, bU0,bU1,bU2, -1, xE, -1, xE, 0);
        BLK(3, 51, aU0,aU1,aU2, cU0,cU1,cU2,  0, xE, -1, xE, 0);
    }

    // ---- main: 16 blocks, PB every other block (16-step rounds) ----
    BLK( 4, 48, bU0,bU1,bU2, aU0,aU1,aU2, -1, xE, -1, xE, 1);
    BLK( 5, 51, cU0,cU1,cU2, bU0,bU1,bU2,  1, xO,  0, xE, 1);
    BLK( 6, 51, aU0,aU1,aU2, cU0,cU1,cU2, -1, xE, -1, xE, 1);
    BLK( 7, 51, bU0,bU1,bU2, aU0,aU1,aU2,  2, xE,  1, xO, 1);
    BLK( 8, 51, cU0,cU1,cU2, bU0,bU1,bU2, -1, xE, -1, xE, 1);
    BLK( 9, 51, aU0,aU1,aU2, cU0,cU1,cU2,  3, xO,  2, xE, 1);
    BLK(10, 51, bU0,bU1,bU2, aU0,aU1,aU2, -1, xE, -1, xE, 1);
    BLK(11, 51, cU0,cU1,cU2, bU0,bU1,bU2,  4, xE,  3, xO, 1);
    BLK(12, 51, aU0,aU1,aU2, cU0,cU1,cU2, -1, xE, -1, xE, 1);
    BLK(13, 51, bU0,bU1,bU2, aU0,aU1,aU2,  5, xO,  4, xE, 1);
    BLK(14, 51, cU0,cU1,cU2, bU0,bU1,bU2, -1, xE, -1, xE, 1);
    BLK(15, 51, aU0,aU1,aU2, cU0,cU1,cU2,  6, xE,  5, xO, 1);
    BLK(16, 51, bU0,bU1,bU2, aU0,aU1,aU2, -1, xE, -1, xE, 1);
    BLK(17, 51, cU0,cU1,cU2, bU0,bU1,bU2,  7, xO,  6, xE, 1);
    BLK(18, 27, aU0,aU1,aU2, cU0,cU1,cU2, -1, xE, -1, xE, 1);
    BLK(19,  0, bU0,bU1,bU2, aU0,aU1,aU2, -1, xE,  7, xO, 1);

#undef ISSUE_L
#undef ISSUE_X
#undef BLK
}

extern "C" void kernel_launch(void* const* d_in, const int* in_sizes, int n_in,
                              void* d_out, int out_size, void* d_ws, size_t ws_size,
                              hipStream_t stream) {
    const float* x  = (const float*)d_in[0];
    const float* u  = (const float*)d_in[1];
    const float* W1 = (const float*)d_in[2];
    const float* W2 = (const float*)d_in[3];
    const float* W3 = (const float*)d_in[4];
    float* out = (float*)d_out;

    hipLaunchKernelGGL(fastnet_kernel, dim3(NCH), dim3(64), 0, stream,
                       x, u, W1, W2, W3, out);
}

// Round 8
// 37.875 us; speedup vs baseline: 1.2202x; 1.2202x over previous
//
#include <hip/hip_runtime.h>
#include <hip/hip_fp16.h>

typedef _Float16 h2 __attribute__((ext_vector_type(2)));

#define NCH   1024                 // chunks; one 128-thread wg (2 waves) per chunk
#define CL    256                  // outputs per chunk
#define HALO  32                   // warm-up steps (empirically exact since R4)
#define SPB   8                    // steps per staged block
#define NB    36                   // (HALO+CL)/SPB
#define BH    4                    // halo blocks
#define TROW  141                  // traj row stride in dwords (odd -> conflict-free)

#if __has_builtin(__builtin_amdgcn_exp2f)
#define EXP2F __builtin_amdgcn_exp2f
#else
#define EXP2F exp2f
#endif
#if __has_builtin(__builtin_amdgcn_rcpf)
#define RCPF __builtin_amdgcn_rcpf
#else
#define RCPF(x) (1.0f / (x))
#endif

#define A_K   (-14.4269504088896341f)   /* -10*log2(e) */
#define UPC_K (7.21347520444481704f)    /* -A_K*0.5    */
#define K2_K  (2.8853900817779268f)     /* 2*log2(e)   */

__device__ __forceinline__ h2 pkrtz(float a, float b) {
    return __builtin_bit_cast(h2, __builtin_amdgcn_cvt_pkrtz(a, b));
}
__device__ __forceinline__ float sigstep(float w, float up) {
    return RCPF(1.0f + EXP2F(__builtin_fmaf(A_K, w, up)));
}
__device__ __forceinline__ float fold(float u) {
    return __builtin_fmaf(A_K, u, UPC_K);
}
__device__ __forceinline__ uint32_t pk16(float a, float b) {
    return __builtin_bit_cast(uint32_t, pkrtz(a, b));
}
__device__ __forceinline__ float tanh32(float z) {           // tanh = 1 - 2/(e^2z+1)
    return 1.0f - 2.0f * RCPF(1.0f + EXP2F(K2_K * z));
}

__device__ __forceinline__ void gload_lds16(const float* g, float* l) {
    __builtin_amdgcn_global_load_lds(
        (__attribute__((address_space(1))) void*)(void*)g,
        (__attribute__((address_space(3))) void*)(void*)l, 16, 0, 0);
}
__device__ __forceinline__ void gload_lds4(const float* g, float* l) {
    __builtin_amdgcn_global_load_lds(
        (__attribute__((address_space(1))) void*)(void*)g,
        (__attribute__((address_space(3))) void*)(void*)l, 4, 0, 0);
}

#define STR2(x) #x
#define WAITVMn(N) asm volatile("s_waitcnt vmcnt(" STR2(N) ")" ::: "memory")
#define WAITLGKM   asm volatile("s_waitcnt lgkmcnt(0)" ::: "memory")

__global__ void __launch_bounds__(128)
fastnet_kernel(const float* __restrict__ x, const float* __restrict__ u,
               const float* __restrict__ W1, const float* __restrict__ W2,
               const float* __restrict__ W3, float* __restrict__ out) {
    // 8.96 KB u double-buffer + 18.05 KB traj ping-pong = 27.0 KB -> 4 wg/CU,
    // grid of 1024 wgs (2048 waves) exactly resident, 2 waves/SIMD.
    __shared__ __align__(16) float    ubuf[2][SPB * 140];
    __shared__ __align__(16) uint32_t traj[2 * 16 * TROW];

    const int  tid  = threadIdx.x;
    const int  lane = tid & 63;
    const int  wid  = tid >> 6;
    const int  g    = blockIdx.x;
    const int  ch   = ((g & 7) << 7) | (g >> 3);   // bijective XCD swizzle (1024%8==0)
    const long cbase = (long)ch * CL;

    if (wid == 0) {
        // ================= producer wave: weight recurrence =================
        const float* su = u + (cbase - (long)HALO) * 140;
        const int    cl = (lane < 12) ? lane : 11;

        float wa, wb, wc;
        if (ch == 0) {
            wa = (lane < 30) ? W1[lane] : (lane < 130 ? W2[lane - 30] : W3[lane - 130]);
            wb = W2[lane + 34];
            int kc = lane + 128;
            wc = (lane < 12) ? ((kc < 130) ? W2[kc - 30] : W3[kc - 130]) : 0.5f;
        } else {
            wa = wb = wc = 0.5f;
        }

#define STAGE(B_) do {                                                          \
        const float* s_ = su + (long)(B_) * (SPB * 140);                        \
        float* d_ = &ubuf[(B_) & 1][0];                                         \
        _Pragma("unroll")                                                       \
        for (int i_ = 0; i_ < 4; i_++)                                          \
            gload_lds16(s_ + i_ * 256 + lane * 4, d_ + i_ * 256);               \
        gload_lds4(s_ + 1024 + lane, d_ + 1024);                                \
        if (lane < 32) gload_lds4(s_ + 1088 + lane, d_ + 1088);                 \
    } while (0)

        const int b0 = (ch == 0) ? BH : 0;
        STAGE(b0);
        STAGE(b0 + 1);

        for (int b = b0; b < NB; ++b) {
            if (b == NB - 1) { WAITVMn(0); } else { WAITVMn(6); }   // buf[b&1] ready

            const float* ub = &ubuf[b & 1][0];
            float uu0[SPB], uu1[SPB], uu2[SPB];
            #pragma unroll
            for (int t = 0; t < SPB; t++) {
                uu0[t] = ub[t * 140 + lane];
                uu1[t] = ub[t * 140 + 64 + lane];
                uu2[t] = ub[t * 140 + 128 + cl];
            }
            WAITLGKM;                          // reads retired -> buffer reusable
            if (b + 2 < NB) STAGE(b + 2);

            const int rel = b - BH;            // <0 during halo
            uint32_t* tb = &traj[((rel >> 2) & 1) * (16 * TROW) + (rel & 3) * 4 * TROW];
            #pragma unroll
            for (int t = 0; t < SPB; t += 2) {
                wa = sigstep(wa, fold(uu0[t]));
                wb = sigstep(wb, fold(uu1[t]));
                wc = sigstep(wc, fold(uu2[t]));
                float wa0 = wa, wb0 = wb, wc0 = wc;
                wa = sigstep(wa, fold(uu0[t + 1]));
                wb = sigstep(wb, fold(uu1[t + 1]));
                wc = sigstep(wc, fold(uu2[t + 1]));
                if (rel >= 0) {
                    uint32_t* tw = tb + (t >> 1) * TROW + lane;
                    tw[0]  = pk16(wa0, wa);
                    tw[64] = pk16(wb0, wb);
                    if (lane < 12) tw[128] = pk16(wc0, wc);
                }
            }
            // round complete -> publish to consumer. RAW barrier (no vmcnt drain!):
            // only LDS writes need visibility, so lgkmcnt(0) + s_barrier suffices.
            if (rel >= 0 && (rel & 3) == 3) {
                WAITLGKM;
                __builtin_amdgcn_s_barrier();
            }
        }
#undef STAGE
    } else {
        // ================= consumer wave: per-step MLP =================
        for (int r = 0; r < 8; ++r) {
            __builtin_amdgcn_s_barrier();      // round r trajectory ready
            if (lane < 32) {
                const long  gi = cbase + (long)r * 32 + lane;
                const float* xp = x + gi * 3;
                const float x0 = xp[0], x1 = xp[1], x2 = xp[2];
                const uint32_t* tb = &traj[(r & 1) * (16 * TROW) + (lane >> 1) * TROW];
                const int sh = (lane & 1) << 4;      // even step in lo half, odd in hi
#define WC(C_) ((float)__builtin_bit_cast(_Float16, (unsigned short)(tb[C_] >> sh)))
                float h1[10];
                #pragma unroll
                for (int c = 0; c < 10; c++) {
                    float z = x0 * WC(c) + x1 * WC(10 + c) + x2 * WC(20 + c);
                    h1[c] = tanh32(z);
                }
                float hh[10];
                #pragma unroll
                for (int c = 0; c < 10; c++) {
                    float z = h1[0] * WC(30 + c);
                    #pragma unroll
                    for (int k2 = 1; k2 < 10; k2++)
                        z = __builtin_fmaf(h1[k2], WC(30 + k2 * 10 + c), z);
                    hh[c] = tanh32(z);
                }
                float y = hh[0] * WC(130);
                #pragma unroll
                for (int k2 = 1; k2 < 10; k2++)
                    y = __builtin_fmaf(hh[k2], WC(130 + k2), y);
#undef WC
                out[gi] = y;
            }
        }
    }
}

extern "C" void kernel_launch(void* const* d_in, const int* in_sizes, int n_in,
                              void* d_out, int out_size, void* d_ws, size_t ws_size,
                              hipStream_t stream) {
    const float* x  = (const float*)d_in[0];
    const float* u  = (const float*)d_in[1];
    const float* W1 = (const float*)d_in[2];
    const float* W2 = (const float*)d_in[3];
    const float* W3 = (const float*)d_in[4];
    float* out = (float*)d_out;

    hipLaunchKernelGGL(fastnet_kernel, dim3(NCH), dim3(128), 0, stream,
                       x, u, W1, W2, W3, out);
}